// Round 1
// baseline (2865.210 us; speedup 1.0000x reference)
//
#include <hip/hip_runtime.h>

// Problem constants (validated against in_sizes at launch)
constexpr int D    = 128;   // D_IN = D_H
constexpr int DOUT = 64;
constexpr int BN_T = 32;    // tail tile rows

// ---------------------------------------------------------------------------
// SpMM scatter: y[dst] += w * x[src], one wave (64 lanes) per edge, 2 floats/lane
// ---------------------------------------------------------------------------
__global__ __launch_bounds__(256) void spmm_atomic(
    const int* __restrict__ src, const int* __restrict__ dst,
    const float* __restrict__ w, const float* __restrict__ x,
    float* __restrict__ y, int E)
{
    int lane = threadIdx.x & 63;
    int wave = (blockIdx.x * blockDim.x + threadIdx.x) >> 6;
    int nw   = (gridDim.x * blockDim.x) >> 6;
    for (int e = wave; e < E; e += nw) {
        int s   = src[e];
        int d   = dst[e];
        float ww = w[e];
        const float2 v = *reinterpret_cast<const float2*>(x + (size_t)s * D + lane * 2);
        float* yp = y + (size_t)d * D + lane * 2;
        atomicAdd(yp,     ww * v.x);
        atomicAdd(yp + 1, ww * v.y);
    }
}

// ---------------------------------------------------------------------------
// Register-tiled GEMV batch: acc[NPT][4] = X_lds[BN][K] @ W[K][NOUT] (+bias)
// Thread map: cg = tid % (NOUT/4) -> 4 consecutive cols, ng = tid / (NOUT/4)
// ---------------------------------------------------------------------------
template<int K, int NOUT, int NPT>
__device__ inline void gemm_tile(const float* Xlds, int XS,
                                 const float* __restrict__ W,
                                 const float* __restrict__ bias,
                                 int tid, float acc[NPT][4], int& n0, int& c0)
{
    constexpr int CG = NOUT / 4;
    int cg = tid % CG;  c0 = cg * 4;
    int ng = tid / CG;  n0 = ng * NPT;
    if (bias) {
        float4 b4 = *reinterpret_cast<const float4*>(bias + c0);
        #pragma unroll
        for (int i = 0; i < NPT; ++i) {
            acc[i][0] = b4.x; acc[i][1] = b4.y; acc[i][2] = b4.z; acc[i][3] = b4.w;
        }
    } else {
        #pragma unroll
        for (int i = 0; i < NPT; ++i)
            acc[i][0] = acc[i][1] = acc[i][2] = acc[i][3] = 0.f;
    }
    #pragma unroll 4
    for (int k = 0; k < K; ++k) {
        float4 w4 = *reinterpret_cast<const float4*>(W + (size_t)k * NOUT + c0);
        #pragma unroll
        for (int i = 0; i < NPT; ++i) {
            float xv = Xlds[(n0 + i) * XS + k];
            acc[i][0] += xv * w4.x;
            acc[i][1] += xv * w4.y;
            acc[i][2] += xv * w4.z;
            acc[i][3] += xv * w4.w;
        }
    }
}

template<int NPT, bool RELU>
__device__ inline void store_lds(float* Y, int YS, int coloff,
                                 float acc[NPT][4], int n0, int c0)
{
    #pragma unroll
    for (int i = 0; i < NPT; ++i) {
        float4 v;
        v.x = RELU ? fmaxf(acc[i][0], 0.f) : acc[i][0];
        v.y = RELU ? fmaxf(acc[i][1], 0.f) : acc[i][1];
        v.z = RELU ? fmaxf(acc[i][2], 0.f) : acc[i][2];
        v.w = RELU ? fmaxf(acc[i][3], 0.f) : acc[i][3];
        *reinterpret_cast<float4*>(&Y[(n0 + i) * YS + coloff + c0]) = v;
    }
}

// Load a [BN x 128] fp32 tile (row base nb) into LDS with row stride 132, zero-fill OOB rows
template<int BN>
__device__ inline void load_tile128(float* dstLds, const float* __restrict__ src,
                                    int nb, int nN, int tid, int ldsStride, int colOff)
{
    for (int p = tid; p < BN * 32; p += 256) {
        int r  = p >> 5;
        int c4 = (p & 31) << 2;
        float4 v = make_float4(0.f, 0.f, 0.f, 0.f);
        if (nb + r < nN)
            v = *reinterpret_cast<const float4*>(src + (size_t)(nb + r) * 128 + c4);
        *reinterpret_cast<float4*>(&dstLds[r * ldsStride + colOff + c4]) = v;
    }
}

// ---------------------------------------------------------------------------
// conv1 = relu(agg0 @ W1)  [N,128] = [N,128]x[128,128], tile BN=64
// ---------------------------------------------------------------------------
__global__ __launch_bounds__(256) void conv1_gemm(
    const float* __restrict__ Xg, const float* __restrict__ W,
    float* __restrict__ Y, int nN)
{
    __shared__ float Xs[64 * 132];
    int nb  = blockIdx.x * 64;
    int tid = threadIdx.x;
    load_tile128<64>(Xs, Xg, nb, nN, tid, 132, 0);
    __syncthreads();
    float acc[8][4]; int n0, c0;
    gemm_tile<128, 128, 8>(Xs, 132, W, nullptr, tid, acc, n0, c0);
    #pragma unroll
    for (int i = 0; i < 8; ++i) {
        int n = nb + n0 + i;
        if (n < nN) {
            float4 v;
            v.x = fmaxf(acc[i][0], 0.f);
            v.y = fmaxf(acc[i][1], 0.f);
            v.z = fmaxf(acc[i][2], 0.f);
            v.w = fmaxf(acc[i][3], 0.f);
            *reinterpret_cast<float4*>(Y + (size_t)n * 128 + c0) = v;
        }
    }
}

// ---------------------------------------------------------------------------
// Fused tail: self-MLP + conv2 + concat + head MLP
// ---------------------------------------------------------------------------
__global__ __launch_bounds__(256) void tail_kernel(
    const float* __restrict__ feats, const float* __restrict__ conv1,
    const float* __restrict__ agg1,
    const float* __restrict__ Wm1, const float* __restrict__ bm1,
    const float* __restrict__ Wm2, const float* __restrict__ bm2,
    const float* __restrict__ W2,
    const float* __restrict__ Wh1, const float* __restrict__ bh1,
    const float* __restrict__ Wh2, const float* __restrict__ bh2,
    float* __restrict__ out, int nN)
{
    __shared__ float A[BN_T * 132];   // feats -> agg1 -> t
    __shared__ float B[BN_T * 132];   // s1
    __shared__ float Hs[BN_T * 260];  // h = [self_c | conv1 | conv2]
    int nb  = blockIdx.x * BN_T;
    int tid = threadIdx.x;

    // 1. features tile -> A
    load_tile128<BN_T>(A, feats, nb, nN, tid, 132, 0);
    __syncthreads();

    // 2. s1 = relu(A @ Wm1 + bm1) -> B
    {
        float acc[4][4]; int n0, c0;
        gemm_tile<128, 128, 4>(A, 132, Wm1, bm1, tid, acc, n0, c0);
        __syncthreads();           // everyone done reading A? (A reused below)
        store_lds<4, true>(B, 132, 0, acc, n0, c0);
    }
    __syncthreads();

    // 3a. self_c = B @ Wm2 + bm2 -> Hs[:, 0:64]
    {
        float acc[2][4]; int n0, c0;
        gemm_tile<128, 64, 2>(B, 132, Wm2, bm2, tid, acc, n0, c0);
        store_lds<2, false>(Hs, 260, 0, acc, n0, c0);
    }
    // 3b. conv1 tile -> Hs[:, 64:192]; agg1 tile -> A
    load_tile128<BN_T>(Hs, conv1, nb, nN, tid, 260, 64);
    load_tile128<BN_T>(A, agg1, nb, nN, tid, 132, 0);
    __syncthreads();

    // 4. conv2 = A @ W2 -> Hs[:, 192:256]
    {
        float acc[2][4]; int n0, c0;
        gemm_tile<128, 64, 2>(A, 132, W2, nullptr, tid, acc, n0, c0);
        store_lds<2, false>(Hs, 260, 192, acc, n0, c0);
    }
    __syncthreads();

    // 5. t = relu(Hs @ Wh1 + bh1) -> A
    {
        float acc[4][4]; int n0, c0;
        gemm_tile<256, 128, 4>(Hs, 260, Wh1, bh1, tid, acc, n0, c0);
        __syncthreads();           // done reading A (it held agg1) before overwrite
        store_lds<4, true>(A, 132, 0, acc, n0, c0);
    }
    __syncthreads();

    // 6. out = A @ Wh2 + bh2 -> global
    {
        float acc[2][4]; int n0, c0;
        gemm_tile<128, 64, 2>(A, 132, Wh2, bh2, tid, acc, n0, c0);
        #pragma unroll
        for (int i = 0; i < 2; ++i) {
            int n = nb + n0 + i;
            if (n < nN)
                *reinterpret_cast<float4*>(out + (size_t)n * DOUT + c0) =
                    make_float4(acc[i][0], acc[i][1], acc[i][2], acc[i][3]);
        }
    }
}

// ---------------------------------------------------------------------------
extern "C" void kernel_launch(void* const* d_in, const int* in_sizes, int n_in,
                              void* d_out, int out_size, void* d_ws, size_t ws_size,
                              hipStream_t stream)
{
    const float* features = (const float*)d_in[0];
    const int*   esrc     = (const int*)d_in[1];
    const int*   edst     = (const int*)d_in[2];
    const float* ew       = (const float*)d_in[3];
    const float* W1       = (const float*)d_in[4];
    const float* W2       = (const float*)d_in[5];
    const float* Wm1      = (const float*)d_in[6];
    const float* bm1      = (const float*)d_in[7];
    const float* Wm2      = (const float*)d_in[8];
    const float* bm2      = (const float*)d_in[9];
    const float* Wh1      = (const float*)d_in[10];
    const float* bh1      = (const float*)d_in[11];
    const float* Wh2      = (const float*)d_in[12];
    const float* bh2      = (const float*)d_in[13];

    int nN = in_sizes[0] / D;   // 50000
    int E  = in_sizes[1];       // 1.6M
    float* out = (float*)d_out;

    float* B0 = (float*)d_ws;                 // agg0, later agg1  [N,128]
    float* B1 = B0 + (size_t)nN * D;          // conv1             [N,128]
    size_t aggBytes = (size_t)nN * D * sizeof(float);

    // agg0 = spmm(adj, features)
    hipMemsetAsync(B0, 0, aggBytes, stream);
    spmm_atomic<<<8192, 256, 0, stream>>>(esrc, edst, ew, features, B0, E);

    // conv1 = relu(agg0 @ W1)
    int gB = (nN + 63) / 64;
    conv1_gemm<<<gB, 256, 0, stream>>>(B0, W1, B1, nN);

    // agg1 = spmm(adj, conv1)
    hipMemsetAsync(B0, 0, aggBytes, stream);
    spmm_atomic<<<8192, 256, 0, stream>>>(esrc, edst, ew, B1, B0, E);

    // fused: self-MLP, conv2, concat, head
    int tB = (nN + BN_T - 1) / BN_T;
    tail_kernel<<<tB, 256, 0, stream>>>(features, B1, B0,
                                        Wm1, bm1, Wm2, bm2, W2,
                                        Wh1, bh1, Wh2, bh2, out, nN);
}

// Round 2
// 683.516 us; speedup vs baseline: 4.1919x; 4.1919x over previous
//
#include <hip/hip_runtime.h>

constexpr int D    = 128;   // D_IN = D_H
constexpr int DOUT = 64;
constexpr int BN_T = 32;    // tail tile rows

// ===========================================================================
// CSR build: histogram -> scan -> scatter
// ===========================================================================
__global__ __launch_bounds__(256) void hist_kernel(
    const int* __restrict__ dst, int* __restrict__ deg, int E)
{
    int i = blockIdx.x * blockDim.x + threadIdx.x;
    int ns = gridDim.x * blockDim.x;
    for (int e = i; e < E; e += ns)
        atomicAdd(&deg[dst[e]], 1);
}

__global__ __launch_bounds__(1024) void scan_kernel(
    const int* __restrict__ deg, int* __restrict__ rowptr, int n)
{
    __shared__ int sm[1024];
    __shared__ int s_carry;
    int tid = threadIdx.x;
    if (tid == 0) s_carry = 0;
    __syncthreads();
    for (int base = 0; base < n; base += 1024) {
        int i = base + tid;
        int v = (i < n) ? deg[i] : 0;
        sm[tid] = v;
        __syncthreads();
        #pragma unroll
        for (int off = 1; off < 1024; off <<= 1) {
            int t = (tid >= off) ? sm[tid - off] : 0;
            __syncthreads();
            sm[tid] += t;
            __syncthreads();
        }
        int carry = s_carry;
        if (i < n) rowptr[i] = carry + sm[tid] - v;   // exclusive
        __syncthreads();
        if (tid == 1023) s_carry = carry + sm[1023];
        __syncthreads();
    }
    if (tid == 0) rowptr[n] = s_carry;
}

__global__ __launch_bounds__(256) void scatter_kernel(
    const int* __restrict__ src, const int* __restrict__ dst,
    const float* __restrict__ w, int* __restrict__ cursor,
    int* __restrict__ psrc, float* __restrict__ pw, int E)
{
    int i = blockIdx.x * blockDim.x + threadIdx.x;
    int ns = gridDim.x * blockDim.x;
    for (int e = i; e < E; e += ns) {
        int d = dst[e];
        int pos = atomicAdd(&cursor[d], 1);
        psrc[pos] = src[e];
        pw[pos]   = w[e];
    }
}

// ===========================================================================
// CSR SpMM (gather form): one wave per dst row
// ===========================================================================
template<int WIDTH, bool RELU>
__global__ __launch_bounds__(256) void spmm_csr(
    const int* __restrict__ rowptr, const int* __restrict__ psrc,
    const float* __restrict__ pw, const float* __restrict__ x,
    float* __restrict__ y, int nN)
{
    int lane = threadIdx.x & 63;
    int row  = (blockIdx.x * blockDim.x + threadIdx.x) >> 6;
    if (row >= nN) return;
    int rs = rowptr[row], re = rowptr[row + 1];

    float acc0 = 0.f, acc1 = 0.f;
    for (int base = rs; base < re; base += 64) {
        int e = base + lane;
        int sj = 0; float wj = 0.f;
        if (e < re) { sj = psrc[e]; wj = pw[e]; }
        int cnt = min(64, re - base);
        int j = 0;
        for (; j + 4 <= cnt; j += 4) {
            int   s0 = __shfl(sj, j+0), s1 = __shfl(sj, j+1),
                  s2 = __shfl(sj, j+2), s3 = __shfl(sj, j+3);
            float w0 = __shfl(wj, j+0), w1 = __shfl(wj, j+1),
                  w2 = __shfl(wj, j+2), w3 = __shfl(wj, j+3);
            if (WIDTH == 128) {
                float2 v0 = *reinterpret_cast<const float2*>(x + (size_t)s0*128 + lane*2);
                float2 v1 = *reinterpret_cast<const float2*>(x + (size_t)s1*128 + lane*2);
                float2 v2 = *reinterpret_cast<const float2*>(x + (size_t)s2*128 + lane*2);
                float2 v3 = *reinterpret_cast<const float2*>(x + (size_t)s3*128 + lane*2);
                acc0 += w0*v0.x; acc1 += w0*v0.y;
                acc0 += w1*v1.x; acc1 += w1*v1.y;
                acc0 += w2*v2.x; acc1 += w2*v2.y;
                acc0 += w3*v3.x; acc1 += w3*v3.y;
            } else {
                float v0 = x[(size_t)s0*64 + lane];
                float v1 = x[(size_t)s1*64 + lane];
                float v2 = x[(size_t)s2*64 + lane];
                float v3 = x[(size_t)s3*64 + lane];
                acc0 += w0*v0 + w1*v1 + w2*v2 + w3*v3;
            }
        }
        for (; j < cnt; ++j) {
            int   s = __shfl(sj, j);
            float ww = __shfl(wj, j);
            if (WIDTH == 128) {
                float2 v = *reinterpret_cast<const float2*>(x + (size_t)s*128 + lane*2);
                acc0 += ww*v.x; acc1 += ww*v.y;
            } else {
                acc0 += ww * x[(size_t)s*64 + lane];
            }
        }
    }
    if (WIDTH == 128) {
        float2 o;
        o.x = RELU ? fmaxf(acc0, 0.f) : acc0;
        o.y = RELU ? fmaxf(acc1, 0.f) : acc1;
        *reinterpret_cast<float2*>(y + (size_t)row*128 + lane*2) = o;
    } else {
        y[(size_t)row*64 + lane] = RELU ? fmaxf(acc0, 0.f) : acc0;
    }
}

// ===========================================================================
// Atomic SpMM (fallback path only)
// ===========================================================================
template<int WIDTH>
__global__ __launch_bounds__(256) void spmm_atomic(
    const int* __restrict__ src, const int* __restrict__ dst,
    const float* __restrict__ w, const float* __restrict__ x,
    float* __restrict__ y, int E)
{
    int lane = threadIdx.x & 63;
    int wave = (blockIdx.x * blockDim.x + threadIdx.x) >> 6;
    int nw   = (gridDim.x * blockDim.x) >> 6;
    for (int e = wave; e < E; e += nw) {
        int s = src[e]; int d = dst[e]; float ww = w[e];
        if (WIDTH == 128) {
            const float2 v = *reinterpret_cast<const float2*>(x + (size_t)s*128 + lane*2);
            float* yp = y + (size_t)d*128 + lane*2;
            atomicAdd(yp,     ww * v.x);
            atomicAdd(yp + 1, ww * v.y);
        } else {
            atomicAdd(y + (size_t)d*64 + lane, ww * x[(size_t)s*64 + lane]);
        }
    }
}

__global__ __launch_bounds__(256) void relu_kernel(float* __restrict__ p, int n4)
{
    int i = blockIdx.x * blockDim.x + threadIdx.x;
    int ns = gridDim.x * blockDim.x;
    for (int k = i; k < n4; k += ns) {
        float4 v = reinterpret_cast<float4*>(p)[k];
        v.x = fmaxf(v.x, 0.f); v.y = fmaxf(v.y, 0.f);
        v.z = fmaxf(v.z, 0.f); v.w = fmaxf(v.w, 0.f);
        reinterpret_cast<float4*>(p)[k] = v;
    }
}

// ===========================================================================
// Dense GEMM pieces (GEMV-batch style, K=128 staged in LDS)
// ===========================================================================
template<int K, int NOUT, int NPT>
__device__ inline void gemm_tile(const float* Xlds, int XS,
                                 const float* __restrict__ W,
                                 const float* __restrict__ bias,
                                 int tid, float acc[NPT][4], int& n0, int& c0)
{
    constexpr int CG = NOUT / 4;
    int cg = tid % CG;  c0 = cg * 4;
    int ng = tid / CG;  n0 = ng * NPT;
    if (bias) {
        float4 b4 = *reinterpret_cast<const float4*>(bias + c0);
        #pragma unroll
        for (int i = 0; i < NPT; ++i) {
            acc[i][0] = b4.x; acc[i][1] = b4.y; acc[i][2] = b4.z; acc[i][3] = b4.w;
        }
    } else {
        #pragma unroll
        for (int i = 0; i < NPT; ++i)
            acc[i][0] = acc[i][1] = acc[i][2] = acc[i][3] = 0.f;
    }
    #pragma unroll 4
    for (int k = 0; k < K; ++k) {
        float4 w4 = *reinterpret_cast<const float4*>(W + (size_t)k * NOUT + c0);
        #pragma unroll
        for (int i = 0; i < NPT; ++i) {
            float xv = Xlds[(n0 + i) * XS + k];
            acc[i][0] += xv * w4.x;
            acc[i][1] += xv * w4.y;
            acc[i][2] += xv * w4.z;
            acc[i][3] += xv * w4.w;
        }
    }
}

template<int NPT, bool RELU>
__device__ inline void store_lds(float* Y, int YS, int coloff,
                                 float acc[NPT][4], int n0, int c0)
{
    #pragma unroll
    for (int i = 0; i < NPT; ++i) {
        float4 v;
        v.x = RELU ? fmaxf(acc[i][0], 0.f) : acc[i][0];
        v.y = RELU ? fmaxf(acc[i][1], 0.f) : acc[i][1];
        v.z = RELU ? fmaxf(acc[i][2], 0.f) : acc[i][2];
        v.w = RELU ? fmaxf(acc[i][3], 0.f) : acc[i][3];
        *reinterpret_cast<float4*>(&Y[(n0 + i) * YS + coloff + c0]) = v;
    }
}

template<int BN>
__device__ inline void load_tile128(float* dstLds, const float* __restrict__ src,
                                    int nb, int nN, int tid, int ldsStride, int colOff)
{
    for (int p = tid; p < BN * 32; p += 256) {
        int r  = p >> 5;
        int c4 = (p & 31) << 2;
        float4 v = make_float4(0.f, 0.f, 0.f, 0.f);
        if (nb + r < nN)
            v = *reinterpret_cast<const float4*>(src + (size_t)(nb + r) * 128 + c4);
        *reinterpret_cast<float4*>(&dstLds[r * ldsStride + colOff + c4]) = v;
    }
}

template<int BN>
__device__ inline void load_tile64(float* dstLds, const float* __restrict__ src,
                                   int nb, int nN, int tid, int ldsStride, int colOff)
{
    for (int p = tid; p < BN * 16; p += 256) {
        int r  = p >> 4;
        int c4 = (p & 15) << 2;
        float4 v = make_float4(0.f, 0.f, 0.f, 0.f);
        if (nb + r < nN)
            v = *reinterpret_cast<const float4*>(src + (size_t)(nb + r) * 64 + c4);
        *reinterpret_cast<float4*>(&dstLds[r * ldsStride + colOff + c4]) = v;
    }
}

// Y[N,NOUT] = X[N,128] @ W[128,NOUT], optional relu  (tile BN=64)
template<int NOUT, bool RELU>
__global__ __launch_bounds__(256) void dense_gemm(
    const float* __restrict__ Xg, const float* __restrict__ W,
    float* __restrict__ Y, int nN)
{
    __shared__ float Xs[64 * 132];
    int nb  = blockIdx.x * 64;
    int tid = threadIdx.x;
    load_tile128<64>(Xs, Xg, nb, nN, tid, 132, 0);
    __syncthreads();
    constexpr int NPT = NOUT / 16;   // 128->8, 64->4 (covers 64 rows w/ 256 thr)
    float acc[NPT][4]; int n0, c0;
    gemm_tile<128, NOUT, NPT>(Xs, 132, W, nullptr, tid, acc, n0, c0);
    #pragma unroll
    for (int i = 0; i < NPT; ++i) {
        int n = nb + n0 + i;
        if (n < nN) {
            float4 v;
            v.x = RELU ? fmaxf(acc[i][0], 0.f) : acc[i][0];
            v.y = RELU ? fmaxf(acc[i][1], 0.f) : acc[i][1];
            v.z = RELU ? fmaxf(acc[i][2], 0.f) : acc[i][2];
            v.w = RELU ? fmaxf(acc[i][3], 0.f) : acc[i][3];
            *reinterpret_cast<float4*>(Y + (size_t)n * NOUT + c0) = v;
        }
    }
}

// ===========================================================================
// Fused tail: self-MLP + concat(self, conv1, conv2) + head MLP
// ===========================================================================
__global__ __launch_bounds__(256) void tail_kernel(
    const float* __restrict__ feats, const float* __restrict__ conv1,
    const float* __restrict__ conv2,
    const float* __restrict__ Wm1, const float* __restrict__ bm1,
    const float* __restrict__ Wm2, const float* __restrict__ bm2,
    const float* __restrict__ Wh1, const float* __restrict__ bh1,
    const float* __restrict__ Wh2, const float* __restrict__ bh2,
    float* __restrict__ out, int nN)
{
    __shared__ float A[BN_T * 132];   // feats -> t
    __shared__ float B[BN_T * 132];   // s1
    __shared__ float Hs[BN_T * 260];  // h = [self_c | conv1 | conv2]
    int nb  = blockIdx.x * BN_T;
    int tid = threadIdx.x;

    load_tile128<BN_T>(A, feats, nb, nN, tid, 132, 0);
    __syncthreads();

    // s1 = relu(A @ Wm1 + bm1) -> B
    {
        float acc[4][4]; int n0, c0;
        gemm_tile<128, 128, 4>(A, 132, Wm1, bm1, tid, acc, n0, c0);
        store_lds<4, true>(B, 132, 0, acc, n0, c0);
    }
    __syncthreads();

    // self_c = B @ Wm2 + bm2 -> Hs[:,0:64]; stage conv1/conv2 tiles
    {
        float acc[2][4]; int n0, c0;
        gemm_tile<128, 64, 2>(B, 132, Wm2, bm2, tid, acc, n0, c0);
        store_lds<2, false>(Hs, 260, 0, acc, n0, c0);
    }
    load_tile128<BN_T>(Hs, conv1, nb, nN, tid, 260, 64);
    load_tile64<BN_T>(Hs, conv2, nb, nN, tid, 260, 192);
    __syncthreads();

    // t = relu(Hs @ Wh1 + bh1) -> A  (feats dead)
    {
        float acc[4][4]; int n0, c0;
        gemm_tile<256, 128, 4>(Hs, 260, Wh1, bh1, tid, acc, n0, c0);
        store_lds<4, true>(A, 132, 0, acc, n0, c0);
    }
    __syncthreads();

    // out = A @ Wh2 + bh2
    {
        float acc[2][4]; int n0, c0;
        gemm_tile<128, 64, 2>(A, 132, Wh2, bh2, tid, acc, n0, c0);
        #pragma unroll
        for (int i = 0; i < 2; ++i) {
            int n = nb + n0 + i;
            if (n < nN)
                *reinterpret_cast<float4*>(out + (size_t)n * DOUT + c0) =
                    make_float4(acc[i][0], acc[i][1], acc[i][2], acc[i][3]);
        }
    }
}

// ===========================================================================
extern "C" void kernel_launch(void* const* d_in, const int* in_sizes, int n_in,
                              void* d_out, int out_size, void* d_ws, size_t ws_size,
                              hipStream_t stream)
{
    const float* features = (const float*)d_in[0];
    const int*   esrc     = (const int*)d_in[1];
    const int*   edst     = (const int*)d_in[2];
    const float* ew       = (const float*)d_in[3];
    const float* W1       = (const float*)d_in[4];
    const float* W2       = (const float*)d_in[5];
    const float* Wm1      = (const float*)d_in[6];
    const float* bm1      = (const float*)d_in[7];
    const float* Wm2      = (const float*)d_in[8];
    const float* bm2      = (const float*)d_in[9];
    const float* Wh1      = (const float*)d_in[10];
    const float* bh1      = (const float*)d_in[11];
    const float* Wh2      = (const float*)d_in[12];
    const float* bh2      = (const float*)d_in[13];

    int nN = in_sizes[0] / D;   // 50000
    int E  = in_sizes[1];       // 1.6M
    float* out = (float*)d_out;

    size_t nFloats = (size_t)nN * D;                    // per [N,128] buffer
    size_t needMain = 2 * nFloats * 4 + (size_t)E * 8 + (size_t)(2 * nN + 2) * 4;

    float* B0 = (float*)d_ws;             // t1 -> {t2 | conv2}
    float* B1 = B0 + nFloats;             // conv1

    int gGemm = (nN + 63) / 64;
    int gSpmm = (nN + 3) / 4;             // 4 rows (waves) per 256-thr block
    int gTail = (nN + BN_T - 1) / BN_T;

    if (ws_size >= needMain) {
        // ---------------- CSR gather path ----------------
        float* Pw     = B1 + nFloats;                 // [E]
        int*   Psrc   = (int*)(Pw + E);               // [E]
        int*   rowptr = Psrc + E;                     // [nN+1]
        int*   cursor = rowptr + nN + 1;              // [nN]

        hipMemsetAsync(cursor, 0, (size_t)nN * 4, stream);
        hist_kernel<<<1024, 256, 0, stream>>>(edst, cursor, E);
        scan_kernel<<<1, 1024, 0, stream>>>(cursor, rowptr, nN);
        hipMemcpyAsync(cursor, rowptr, (size_t)nN * 4, hipMemcpyDeviceToDevice, stream);
        scatter_kernel<<<1024, 256, 0, stream>>>(esrc, edst, ew, cursor, Psrc, Pw, E);

        // t1 = X @ W1
        dense_gemm<128, false><<<gGemm, 256, 0, stream>>>(features, W1, B0, nN);
        // conv1 = relu(A . t1)
        spmm_csr<128, true><<<gSpmm, 256, 0, stream>>>(rowptr, Psrc, Pw, B0, B1, nN);
        // t2 = conv1 @ W2   (width-64: halves 2nd spmm traffic)
        dense_gemm<64, false><<<gGemm, 256, 0, stream>>>(B1, W2, B0, nN);
        // conv2 = A . t2
        float* conv2 = B0 + (size_t)nN * 64;
        spmm_csr<64, false><<<gSpmm, 256, 0, stream>>>(rowptr, Psrc, Pw, B0, conv2, nN);

        tail_kernel<<<gTail, 256, 0, stream>>>(features, B1, conv2,
                                               Wm1, bm1, Wm2, bm2,
                                               Wh1, bh1, Wh2, bh2, out, nN);
    } else {
        // ---------------- atomic fallback (fits 2 buffers) ----------------
        dense_gemm<128, false><<<gGemm, 256, 0, stream>>>(features, W1, B0, nN); // t1
        hipMemsetAsync(B1, 0, nFloats * 4, stream);
        spmm_atomic<128><<<8192, 256, 0, stream>>>(esrc, edst, ew, B0, B1, E);   // agg1
        relu_kernel<<<2048, 256, 0, stream>>>(B1, (int)(nFloats / 4));           // conv1
        dense_gemm<64, false><<<gGemm, 256, 0, stream>>>(B1, W2, B0, nN);        // t2
        float* conv2 = B0 + (size_t)nN * 64;
        hipMemsetAsync(conv2, 0, (size_t)nN * 64 * 4, stream);
        spmm_atomic<64><<<8192, 256, 0, stream>>>(esrc, edst, ew, B0, conv2, E);
        tail_kernel<<<gTail, 256, 0, stream>>>(features, B1, conv2,
                                               Wm1, bm1, Wm2, bm2,
                                               Wh1, bh1, Wh2, bh2, out, nN);
    }
}

// Round 3
// 363.426 us; speedup vs baseline: 7.8839x; 1.8808x over previous
//
#include <hip/hip_runtime.h>

typedef float  f32x4 __attribute__((ext_vector_type(4)));
typedef short  s16x8 __attribute__((ext_vector_type(8)));
typedef unsigned short u16;
typedef unsigned int   u32;

constexpr int D    = 128;
constexpr int DOUT = 64;

// ---------------------------------------------------------------------------
// bf16 helpers (RTNE)
// ---------------------------------------------------------------------------
__device__ inline u16 f2bf(float f) {
    u32 x = __float_as_uint(f);
    u32 r = (x + 0x7fffu + ((x >> 16) & 1u)) >> 16;
    return (u16)r;
}
__device__ inline float bflo(u32 u) { return __uint_as_float(u << 16); }
__device__ inline float bfhi(u32 u) { return __uint_as_float(u & 0xffff0000u); }

// ---------------------------------------------------------------------------
// features fp32 -> bf16 (8 floats / thread)
// ---------------------------------------------------------------------------
__global__ __launch_bounds__(256) void cvt_bf16_kernel(
    const float* __restrict__ x, u16* __restrict__ y, int n8)
{
    int i = blockIdx.x * blockDim.x + threadIdx.x;
    int ns = gridDim.x * blockDim.x;
    for (int k = i; k < n8; k += ns) {
        float4 a = reinterpret_cast<const float4*>(x)[k * 2];
        float4 b = reinterpret_cast<const float4*>(x)[k * 2 + 1];
        uint4 o;
        o.x = (u32)f2bf(a.x) | ((u32)f2bf(a.y) << 16);
        o.y = (u32)f2bf(a.z) | ((u32)f2bf(a.w) << 16);
        o.z = (u32)f2bf(b.x) | ((u32)f2bf(b.y) << 16);
        o.w = (u32)f2bf(b.z) | ((u32)f2bf(b.w) << 16);
        reinterpret_cast<uint4*>(y)[k] = o;
    }
}

// ---------------------------------------------------------------------------
// Repack fp32 weight [K x NOUT] into MFMA B-fragment-linear bf16 layout:
//   Wf[((kk*NT + nt)*64 + lane)*8 + j] = bf16( W[(kk*32+(lane>>4)*8+j)*NOUT + nt*16+(lane&15)] )
// ---------------------------------------------------------------------------
__global__ __launch_bounds__(256) void repack_kernel(
    const float* __restrict__ W, u16* __restrict__ Wf, int KK, int NT, int NOUT)
{
    int t = blockIdx.x * blockDim.x + threadIdx.x;
    int total = KK * NT * 64;
    if (t >= total) return;
    int kk   = t / (NT * 64);
    int rem  = t % (NT * 64);
    int nt   = rem / 64;
    int lane = rem % 64;
    int k0 = kk * 32 + ((lane >> 4) << 3);
    int c  = nt * 16 + (lane & 15);
    #pragma unroll
    for (int j = 0; j < 8; ++j)
        Wf[(size_t)t * 8 + j] = f2bf(W[(size_t)(k0 + j) * NOUT + c]);
}

// ---------------------------------------------------------------------------
// CSR build: hist -> 3-phase scan -> scatter
// ---------------------------------------------------------------------------
__global__ __launch_bounds__(256) void hist_kernel(
    const int* __restrict__ dst, int* __restrict__ deg, int E)
{
    int i = blockIdx.x * blockDim.x + threadIdx.x;
    int ns = gridDim.x * blockDim.x;
    for (int e = i; e < E; e += ns) atomicAdd(&deg[dst[e]], 1);
}

__global__ __launch_bounds__(1024) void scan1_kernel(
    int* __restrict__ data, int* __restrict__ bsum, int n)
{
    __shared__ int sm[1024];
    int tid = threadIdx.x;
    int i = blockIdx.x * 1024 + tid;
    int v = (i < n) ? data[i] : 0;
    sm[tid] = v;
    __syncthreads();
    #pragma unroll
    for (int off = 1; off < 1024; off <<= 1) {
        int t = (tid >= off) ? sm[tid - off] : 0;
        __syncthreads();
        sm[tid] += t;
        __syncthreads();
    }
    if (i < n) data[i] = sm[tid] - v;          // exclusive within chunk
    if (tid == 1023) bsum[blockIdx.x] = sm[1023];
}

__global__ __launch_bounds__(64) void scan2_kernel(
    const int* __restrict__ bsum, int* __restrict__ boff, int nb, int* __restrict__ totalOut)
{
    int tid = threadIdx.x;
    int v = (tid < nb) ? bsum[tid] : 0;
    int x = v;
    #pragma unroll
    for (int off = 1; off < 64; off <<= 1) {
        int t = __shfl_up(x, off);
        if (tid >= off) x += t;
    }
    if (tid < nb) boff[tid] = x - v;
    if (tid == 63) *totalOut = x;
}

__global__ __launch_bounds__(256) void scan3_kernel(
    const int* __restrict__ data, const int* __restrict__ boff,
    int* __restrict__ rowptr, int* __restrict__ cursor, int n)
{
    int i = blockIdx.x * blockDim.x + threadIdx.x;
    if (i < n) {
        int v = data[i] + boff[i >> 10];
        rowptr[i] = v;
        cursor[i] = v;
    }
}

__global__ __launch_bounds__(256) void scatter_kernel(
    const int* __restrict__ src, const int* __restrict__ dst,
    const float* __restrict__ w, int* __restrict__ cursor,
    int* __restrict__ psrc, float* __restrict__ pw, int E)
{
    int i = blockIdx.x * blockDim.x + threadIdx.x;
    int ns = gridDim.x * blockDim.x;
    for (int e = i; e < E; e += ns) {
        int d = dst[e];
        int pos = atomicAdd(&cursor[d], 1);
        psrc[pos] = src[e];
        pw[pos]   = w[e];
    }
}

// ---------------------------------------------------------------------------
// MFMA building blocks (wave-independent 16-row strips)
// ---------------------------------------------------------------------------
template<int WIDTH, int SA>
__device__ inline void stage_tile(u16* Atile, const u16* __restrict__ src,
                                  int rowbase, int nN, int lane, int colOff)
{
    constexpr int BPR   = WIDTH * 2;          // bytes per row
    constexpr int ITERS = (16 * BPR) / 1024;  // 64 lanes x 16B
    #pragma unroll
    for (int it = 0; it < ITERS; ++it) {
        int flat = it * 1024 + lane * 16;
        int row  = flat / BPR;
        int colS = (flat % BPR) >> 1;
        int4 v = make_int4(0, 0, 0, 0);
        int gr = rowbase + row;
        if (gr < nN)
            v = *reinterpret_cast<const int4*>(src + (size_t)gr * WIDTH + colS);
        *reinterpret_cast<int4*>(Atile + row * SA + colOff + colS) = v;
    }
}

template<int NT>
__device__ inline void init_acc(f32x4* acc, const float* __restrict__ bias, int lane)
{
    #pragma unroll
    for (int nt = 0; nt < NT; ++nt) {
        float bv = bias ? bias[nt * 16 + (lane & 15)] : 0.f;
        acc[nt] = (f32x4){bv, bv, bv, bv};
    }
}

template<int KK, int NT, int SA>
__device__ inline void mfma_pass(const u16* Atile, const u16* __restrict__ Wf,
                                 int lane, f32x4* acc)
{
    const u16* ap = Atile + (lane & 15) * SA + ((lane >> 4) << 3);
    #pragma unroll
    for (int kk = 0; kk < KK; ++kk) {
        s16x8 a = *reinterpret_cast<const s16x8*>(ap + kk * 32);
        #pragma unroll
        for (int nt = 0; nt < NT; ++nt) {
            s16x8 b = *reinterpret_cast<const s16x8*>(Wf + ((size_t)(kk * NT + nt) * 64 + lane) * 8);
            acc[nt] = __builtin_amdgcn_mfma_f32_16x16x32_bf16(a, b, acc[nt], 0, 0, 0);
        }
    }
}

template<int NT, int SA, bool RELU>
__device__ inline void store_c_lds(u16* Btile, f32x4* acc, int lane)
{
    int r0 = (lane >> 4) << 2;
    int c  = lane & 15;
    #pragma unroll
    for (int nt = 0; nt < NT; ++nt)
        #pragma unroll
        for (int i = 0; i < 4; ++i) {
            float v = acc[nt][i];
            if (RELU) v = fmaxf(v, 0.f);
            Btile[(r0 + i) * SA + nt * 16 + c] = f2bf(v);
        }
}

template<int NT, int NOUT, bool RELU, bool OBF16>
__device__ inline void store_c_global(void* Y, f32x4* acc, int rowbase, int nN, int lane)
{
    int r0 = rowbase + ((lane >> 4) << 2);
    int c  = lane & 15;
    #pragma unroll
    for (int nt = 0; nt < NT; ++nt) {
        int col = nt * 16 + c;
        #pragma unroll
        for (int i = 0; i < 4; ++i) {
            int r = r0 + i;
            if (r < nN) {
                float v = acc[nt][i];
                if (RELU) v = fmaxf(v, 0.f);
                if (OBF16) ((u16*)Y)[(size_t)r * NOUT + col] = f2bf(v);
                else       ((float*)Y)[(size_t)r * NOUT + col] = v;
            }
        }
    }
}

// Y[N,NOUT] = X[N,K](bf16) @ Wf (frag-packed), optional bias/relu
template<int K, int NOUT, bool RELU, bool OBF16>
__global__ __launch_bounds__(256) void gemm_mfma(
    const u16* __restrict__ Xb, const u16* __restrict__ Wf,
    const float* __restrict__ bias, void* __restrict__ Y, int nN)
{
    constexpr int SA = K + 8;
    __shared__ __align__(16) u16 As[4 * 16 * SA];
    int tid = threadIdx.x, w = tid >> 6, lane = tid & 63;
    int rowbase = blockIdx.x * 64 + w * 16;
    u16* At = As + w * 16 * SA;
    stage_tile<K, SA>(At, Xb, rowbase, nN, lane, 0);
    __syncthreads();
    f32x4 acc[NOUT / 16];
    init_acc<NOUT / 16>(acc, bias, lane);
    mfma_pass<K / 32, NOUT / 16, SA>(At, Wf, lane, acc);
    store_c_global<NOUT / 16, NOUT, RELU, OBF16>(Y, acc, rowbase, nN, lane);
}

// self path: s_c = relu(xb@Wm1+bm1) @ Wm2 + bm2   -> bf16 [N,64]
__global__ __launch_bounds__(256) void self_mlp_kernel(
    const u16* __restrict__ Xb, const u16* __restrict__ Wm1f, const float* __restrict__ bm1,
    const u16* __restrict__ Wm2f, const float* __restrict__ bm2,
    u16* __restrict__ Yb, int nN)
{
    constexpr int SA = 136;
    __shared__ __align__(16) u16 As[4 * 16 * SA];
    __shared__ __align__(16) u16 Bs[4 * 16 * SA];
    int tid = threadIdx.x, w = tid >> 6, lane = tid & 63;
    int rowbase = blockIdx.x * 64 + w * 16;
    u16* At = As + w * 16 * SA;
    u16* Bt = Bs + w * 16 * SA;
    stage_tile<128, SA>(At, Xb, rowbase, nN, lane, 0);
    __syncthreads();
    {
        f32x4 acc[8];
        init_acc<8>(acc, bm1, lane);
        mfma_pass<4, 8, SA>(At, Wm1f, lane, acc);
        store_c_lds<8, SA, true>(Bt, acc, lane);
    }
    __syncthreads();
    {
        f32x4 acc[4];
        init_acc<4>(acc, bm2, lane);
        mfma_pass<4, 4, SA>(Bt, Wm2f, lane, acc);
        store_c_global<4, 64, false, true>(Yb, acc, rowbase, nN, lane);
    }
}

// tail: out = relu([s_c|conv1|conv2]@Wh1+bh1) @ Wh2 + bh2  -> fp32 [N,64]
__global__ __launch_bounds__(256) void tail_mfma_kernel(
    const u16* __restrict__ Sc, const u16* __restrict__ C1, const u16* __restrict__ C2,
    const u16* __restrict__ Wh1f, const float* __restrict__ bh1,
    const u16* __restrict__ Wh2f, const float* __restrict__ bh2,
    float* __restrict__ out, int nN)
{
    constexpr int SA1 = 264, SA2 = 136;
    __shared__ __align__(16) u16 As[4 * 16 * SA1];
    __shared__ __align__(16) u16 Bs[4 * 16 * SA2];
    int tid = threadIdx.x, w = tid >> 6, lane = tid & 63;
    int rowbase = blockIdx.x * 64 + w * 16;
    u16* At = As + w * 16 * SA1;
    u16* Bt = Bs + w * 16 * SA2;
    stage_tile<64,  SA1>(At, Sc, rowbase, nN, lane, 0);
    stage_tile<128, SA1>(At, C1, rowbase, nN, lane, 64);
    stage_tile<64,  SA1>(At, C2, rowbase, nN, lane, 192);
    __syncthreads();
    {
        f32x4 acc[8];
        init_acc<8>(acc, bh1, lane);
        mfma_pass<8, 8, SA1>(At, Wh1f, lane, acc);
        store_c_lds<8, SA2, true>(Bt, acc, lane);
    }
    __syncthreads();
    {
        f32x4 acc[4];
        init_acc<4>(acc, bh2, lane);
        mfma_pass<4, 4, SA2>(Bt, Wh2f, lane, acc);
        store_c_global<4, 64, false, false>(out, acc, rowbase, nN, lane);
    }
}

// ---------------------------------------------------------------------------
// CSR SpMM gather, bf16 x, fp32 accum. width128: 1 row/wave, 2 bf16/lane.
// ---------------------------------------------------------------------------
template<bool RELU>
__global__ __launch_bounds__(256) void spmm128_bf(
    const int* __restrict__ rowptr, const int* __restrict__ psrc,
    const float* __restrict__ pw, const u16* __restrict__ x,
    u16* __restrict__ y, int nN)
{
    int lane = threadIdx.x & 63;
    int row  = (blockIdx.x * blockDim.x + threadIdx.x) >> 6;
    if (row >= nN) return;
    int rs = rowptr[row], re = rowptr[row + 1];
    float a0 = 0.f, a1 = 0.f;
    for (int base = rs; base < re; base += 64) {
        int e = base + lane;
        int sj = 0; float wj = 0.f;
        if (e < re) { sj = psrc[e]; wj = pw[e]; }
        int cnt = min(64, re - base);
        int j = 0;
        for (; j + 4 <= cnt; j += 4) {
            int   s0 = __shfl(sj, j+0), s1 = __shfl(sj, j+1),
                  s2 = __shfl(sj, j+2), s3 = __shfl(sj, j+3);
            float w0 = __shfl(wj, j+0), w1 = __shfl(wj, j+1),
                  w2 = __shfl(wj, j+2), w3 = __shfl(wj, j+3);
            u32 u0 = *reinterpret_cast<const u32*>(x + (size_t)s0 * 128 + lane * 2);
            u32 u1 = *reinterpret_cast<const u32*>(x + (size_t)s1 * 128 + lane * 2);
            u32 u2 = *reinterpret_cast<const u32*>(x + (size_t)s2 * 128 + lane * 2);
            u32 u3 = *reinterpret_cast<const u32*>(x + (size_t)s3 * 128 + lane * 2);
            a0 += w0 * bflo(u0); a1 += w0 * bfhi(u0);
            a0 += w1 * bflo(u1); a1 += w1 * bfhi(u1);
            a0 += w2 * bflo(u2); a1 += w2 * bfhi(u2);
            a0 += w3 * bflo(u3); a1 += w3 * bfhi(u3);
        }
        for (; j < cnt; ++j) {
            int   s = __shfl(sj, j);
            float ww = __shfl(wj, j);
            u32 u = *reinterpret_cast<const u32*>(x + (size_t)s * 128 + lane * 2);
            a0 += ww * bflo(u); a1 += ww * bfhi(u);
        }
    }
    if (RELU) { a0 = fmaxf(a0, 0.f); a1 = fmaxf(a1, 0.f); }
    u32 o = (u32)f2bf(a0) | ((u32)f2bf(a1) << 16);
    *reinterpret_cast<u32*>(y + (size_t)row * 128 + lane * 2) = o;
}

// width64: 2 rows/wave (32-lane halves), 2 bf16/lane
__global__ __launch_bounds__(256) void spmm64_bf(
    const int* __restrict__ rowptr, const int* __restrict__ psrc,
    const float* __restrict__ pw, const u16* __restrict__ x,
    u16* __restrict__ y, int nN)
{
    int lane = threadIdx.x & 63;
    int wp   = (blockIdx.x * blockDim.x + threadIdx.x) >> 6;
    int sub  = lane >> 5, sl = lane & 31;
    int row  = wp * 2 + sub;
    if (wp * 2 >= nN) return;
    bool live = row < nN;
    int rs = live ? rowptr[row] : 0;
    int re = live ? rowptr[row + 1] : 0;
    float a0 = 0.f, a1 = 0.f;
    for (int base = rs; base < re; base += 32) {
        int e = base + sl;
        int sj = 0; float wj = 0.f;
        if (e < re) { sj = psrc[e]; wj = pw[e]; }
        int cnt = min(32, re - base);
        int j = 0;
        for (; j + 4 <= cnt; j += 4) {
            int   s0 = __shfl(sj, j+0, 32), s1 = __shfl(sj, j+1, 32),
                  s2 = __shfl(sj, j+2, 32), s3 = __shfl(sj, j+3, 32);
            float w0 = __shfl(wj, j+0, 32), w1 = __shfl(wj, j+1, 32),
                  w2 = __shfl(wj, j+2, 32), w3 = __shfl(wj, j+3, 32);
            u32 u0 = *reinterpret_cast<const u32*>(x + (size_t)s0 * 64 + sl * 2);
            u32 u1 = *reinterpret_cast<const u32*>(x + (size_t)s1 * 64 + sl * 2);
            u32 u2 = *reinterpret_cast<const u32*>(x + (size_t)s2 * 64 + sl * 2);
            u32 u3 = *reinterpret_cast<const u32*>(x + (size_t)s3 * 64 + sl * 2);
            a0 += w0 * bflo(u0); a1 += w0 * bfhi(u0);
            a0 += w1 * bflo(u1); a1 += w1 * bfhi(u1);
            a0 += w2 * bflo(u2); a1 += w2 * bfhi(u2);
            a0 += w3 * bflo(u3); a1 += w3 * bfhi(u3);
        }
        for (; j < cnt; ++j) {
            int   s = __shfl(sj, j, 32);
            float ww = __shfl(wj, j, 32);
            u32 u = *reinterpret_cast<const u32*>(x + (size_t)s * 64 + sl * 2);
            a0 += ww * bflo(u); a1 += ww * bfhi(u);
        }
    }
    if (live) {
        u32 o = (u32)f2bf(a0) | ((u32)f2bf(a1) << 16);
        *reinterpret_cast<u32*>(y + (size_t)row * 64 + sl * 2) = o;
    }
}

// ===========================================================================
extern "C" void kernel_launch(void* const* d_in, const int* in_sizes, int n_in,
                              void* d_out, int out_size, void* d_ws, size_t ws_size,
                              hipStream_t stream)
{
    const float* features = (const float*)d_in[0];
    const int*   esrc     = (const int*)d_in[1];
    const int*   edst     = (const int*)d_in[2];
    const float* ew       = (const float*)d_in[3];
    const float* W1  = (const float*)d_in[4];
    const float* W2  = (const float*)d_in[5];
    const float* Wm1 = (const float*)d_in[6];
    const float* bm1 = (const float*)d_in[7];
    const float* Wm2 = (const float*)d_in[8];
    const float* bm2 = (const float*)d_in[9];
    const float* Wh1 = (const float*)d_in[10];
    const float* bh1 = (const float*)d_in[11];
    const float* Wh2 = (const float*)d_in[12];
    const float* bh2 = (const float*)d_in[13];

    int nN = in_sizes[0] / D;   // 50000
    int E  = in_sizes[1];       // 1.6M
    float* out = (float*)d_out;

    // ---- workspace bump allocation (16B-aligned) ----
    char* base = (char*)d_ws;
    size_t off = 0;
    auto alloc = [&](size_t bytes) -> char* {
        char* p = base + off;
        off += (bytes + 255) & ~(size_t)255;
        return p;
    };
    u16* xb     = (u16*)alloc((size_t)nN * 128 * 2);  // S0: xb, later conv2b
    u16* t1b    = (u16*)alloc((size_t)nN * 128 * 2);  // S1: t1b, later t2b + s_cb
    u16* conv1b = (u16*)alloc((size_t)nN * 128 * 2);  // S2
    int*   Psrc = (int*)alloc((size_t)E * 4);
    float* Pw   = (float*)alloc((size_t)E * 4);
    int* rowptr = (int*)alloc(((size_t)nN + 1) * 4);
    int* cursor = (int*)alloc((size_t)nN * 4);
    int* tmp    = (int*)alloc((size_t)nN * 4);
    int* bsum   = (int*)alloc(64 * 4);
    int* boff   = (int*)alloc(64 * 4);
    u16* W1f  = (u16*)alloc(4 * 8 * 64 * 8 * 2);
    u16* Wm1f = (u16*)alloc(4 * 8 * 64 * 8 * 2);
    u16* W2f  = (u16*)alloc(4 * 4 * 64 * 8 * 2);
    u16* Wm2f = (u16*)alloc(4 * 4 * 64 * 8 * 2);
    u16* Wh2f = (u16*)alloc(4 * 4 * 64 * 8 * 2);
    u16* Wh1f = (u16*)alloc(8 * 8 * 64 * 8 * 2);
    u16* t2b    = t1b;                       // [N,64] bf16
    u16* s_cb   = t1b + (size_t)nN * 64;     // [N,64] bf16
    u16* conv2b = xb;                        // [N,64] bf16 (xb dead by then)

    // ---- prep: conversions + weight repack ----
    int n8 = nN * 128 / 8;
    cvt_bf16_kernel<<<(n8 + 255) / 256, 256, 0, stream>>>(features, xb, n8);
    repack_kernel<<<(4*8*64 + 255) / 256, 256, 0, stream>>>(W1,  W1f,  4, 8, 128);
    repack_kernel<<<(4*8*64 + 255) / 256, 256, 0, stream>>>(Wm1, Wm1f, 4, 8, 128);
    repack_kernel<<<(4*4*64 + 255) / 256, 256, 0, stream>>>(W2,  W2f,  4, 4, 64);
    repack_kernel<<<(4*4*64 + 255) / 256, 256, 0, stream>>>(Wm2, Wm2f, 4, 4, 64);
    repack_kernel<<<(4*4*64 + 255) / 256, 256, 0, stream>>>(Wh2, Wh2f, 4, 4, 64);
    repack_kernel<<<(8*8*64 + 255) / 256, 256, 0, stream>>>(Wh1, Wh1f, 8, 8, 128);

    // ---- CSR build ----
    hipMemsetAsync(tmp, 0, (size_t)nN * 4, stream);
    hist_kernel<<<1024, 256, 0, stream>>>(edst, tmp, E);
    int nb = (nN + 1023) / 1024;
    scan1_kernel<<<nb, 1024, 0, stream>>>(tmp, bsum, nN);
    scan2_kernel<<<1, 64, 0, stream>>>(bsum, boff, nb, rowptr + nN);
    scan3_kernel<<<(nN + 255) / 256, 256, 0, stream>>>(tmp, boff, rowptr, cursor, nN);
    scatter_kernel<<<1024, 256, 0, stream>>>(esrc, edst, ew, cursor, Psrc, Pw, E);

    int gGemm   = (nN + 63) / 64;
    int gSpmm1  = (nN + 3) / 4;
    int gSpmm64 = ((nN + 1) / 2 + 3) / 4;

    // t1 = xb @ W1
    gemm_mfma<128, 128, false, true><<<gGemm, 256, 0, stream>>>(xb, W1f, nullptr, t1b, nN);
    // conv1 = relu(A . t1)
    spmm128_bf<true><<<gSpmm1, 256, 0, stream>>>(rowptr, Psrc, Pw, t1b, conv1b, nN);
    // t2 = conv1 @ W2   (t1b dead -> overwrite ok)
    gemm_mfma<128, 64, false, true><<<gGemm, 256, 0, stream>>>(conv1b, W2f, nullptr, t2b, nN);
    // self_c = relu(xb@Wm1+bm1)@Wm2+bm2
    self_mlp_kernel<<<gGemm, 256, 0, stream>>>(xb, Wm1f, bm1, Wm2f, bm2, s_cb, nN);
    // conv2 = A . t2   (xb dead -> conv2b aliases xb)
    spmm64_bf<<<gSpmm64, 256, 0, stream>>>(rowptr, Psrc, Pw, t2b, conv2b, nN);
    // out = relu([s_c|conv1|conv2]@Wh1+bh1)@Wh2+bh2
    tail_mfma_kernel<<<gGemm, 256, 0, stream>>>(s_cb, conv1b, conv2b,
                                                Wh1f, bh1, Wh2f, bh2, out, nN);
}

// Round 4
// 293.312 us; speedup vs baseline: 9.7685x; 1.2390x over previous
//
#include <hip/hip_runtime.h>

typedef float  f32x4 __attribute__((ext_vector_type(4)));
typedef short  s16x8 __attribute__((ext_vector_type(8)));
typedef unsigned short u16;
typedef unsigned int   u32;

constexpr int D    = 128;
constexpr int DOUT = 64;

// ---------------------------------------------------------------------------
__device__ inline u16 f2bf(float f) {
    u32 x = __float_as_uint(f);
    u32 r = (x + 0x7fffu + ((x >> 16) & 1u)) >> 16;
    return (u16)r;
}
__device__ inline float bflo(u32 u) { return __uint_as_float(u << 16); }
__device__ inline float bfhi(u32 u) { return __uint_as_float(u & 0xffff0000u); }

// ---------------------------------------------------------------------------
__global__ __launch_bounds__(256) void cvt_bf16_kernel(
    const float* __restrict__ x, u16* __restrict__ y, int n8)
{
    int i = blockIdx.x * blockDim.x + threadIdx.x;
    int ns = gridDim.x * blockDim.x;
    for (int k = i; k < n8; k += ns) {
        float4 a = reinterpret_cast<const float4*>(x)[k * 2];
        float4 b = reinterpret_cast<const float4*>(x)[k * 2 + 1];
        uint4 o;
        o.x = (u32)f2bf(a.x) | ((u32)f2bf(a.y) << 16);
        o.y = (u32)f2bf(a.z) | ((u32)f2bf(a.w) << 16);
        o.z = (u32)f2bf(b.x) | ((u32)f2bf(b.y) << 16);
        o.w = (u32)f2bf(b.z) | ((u32)f2bf(b.w) << 16);
        reinterpret_cast<uint4*>(y)[k] = o;
    }
}

// ---------------------------------------------------------------------------
// One launch repacks all six weights into MFMA B-fragment-linear bf16:
//   Wf[((kk*NT+nt)*64+lane)*8+j] = bf16(W[(kk*32+(lane>>4)*8+j)*NOUT + nt*16+(lane&15)])
// Thread ranges: W1[0,2048) Wm1[2048,4096) W2[4096,5120) Wm2[5120,6144)
//                Wh2[6144,7168) Wh1[7168,11264)
// ---------------------------------------------------------------------------
__global__ __launch_bounds__(256) void repack_all(
    const float* __restrict__ W1,  u16* __restrict__ W1f,
    const float* __restrict__ Wm1, u16* __restrict__ Wm1f,
    const float* __restrict__ W2,  u16* __restrict__ W2f,
    const float* __restrict__ Wm2, u16* __restrict__ Wm2f,
    const float* __restrict__ Wh2, u16* __restrict__ Wh2f,
    const float* __restrict__ Wh1, u16* __restrict__ Wh1f)
{
    int t = blockIdx.x * blockDim.x + threadIdx.x;
    if (t >= 11264) return;
    const float* W; u16* Wf; int NT, NOUT, base;
    if      (t < 2048)  { W = W1;  Wf = W1f;  NT = 8; NOUT = 128; base = 0; }
    else if (t < 4096)  { W = Wm1; Wf = Wm1f; NT = 8; NOUT = 128; base = 2048; }
    else if (t < 5120)  { W = W2;  Wf = W2f;  NT = 4; NOUT = 64;  base = 4096; }
    else if (t < 6144)  { W = Wm2; Wf = Wm2f; NT = 4; NOUT = 64;  base = 5120; }
    else if (t < 7168)  { W = Wh2; Wf = Wh2f; NT = 4; NOUT = 64;  base = 6144; }
    else                { W = Wh1; Wf = Wh1f; NT = 8; NOUT = 128; base = 7168; }
    int lt   = t - base;
    int kk   = lt / (NT * 64);
    int rem  = lt % (NT * 64);
    int nt   = rem / 64;
    int lane = rem % 64;
    int k0 = kk * 32 + ((lane >> 4) << 3);
    int c  = nt * 16 + (lane & 15);
    #pragma unroll
    for (int j = 0; j < 8; ++j)
        Wf[(size_t)lt * 8 + j] = f2bf(W[(size_t)(k0 + j) * NOUT + c]);
}

// ---------------------------------------------------------------------------
// CSR build: hist -> 3-phase scan -> XCD-partitioned packed scatter
// ---------------------------------------------------------------------------
__global__ __launch_bounds__(256) void hist_kernel(
    const int* __restrict__ dst, int* __restrict__ deg, int E)
{
    int i = blockIdx.x * blockDim.x + threadIdx.x;
    int ns = gridDim.x * blockDim.x;
    for (int e = i; e < E; e += ns) atomicAdd(&deg[dst[e]], 1);
}

__global__ __launch_bounds__(1024) void scan1_kernel(
    int* __restrict__ data, int* __restrict__ bsum, int n)
{
    __shared__ int sm[1024];
    int tid = threadIdx.x;
    int i = blockIdx.x * 1024 + tid;
    int v = (i < n) ? data[i] : 0;
    sm[tid] = v;
    __syncthreads();
    #pragma unroll
    for (int off = 1; off < 1024; off <<= 1) {
        int t = (tid >= off) ? sm[tid - off] : 0;
        __syncthreads();
        sm[tid] += t;
        __syncthreads();
    }
    if (i < n) data[i] = sm[tid] - v;
    if (tid == 1023) bsum[blockIdx.x] = sm[1023];
}

__global__ __launch_bounds__(64) void scan2_kernel(
    const int* __restrict__ bsum, int* __restrict__ boff, int nb, int* __restrict__ totalOut)
{
    int tid = threadIdx.x;
    int v = (tid < nb) ? bsum[tid] : 0;
    int x = v;
    #pragma unroll
    for (int off = 1; off < 64; off <<= 1) {
        int t = __shfl_up(x, off);
        if (tid >= off) x += t;
    }
    if (tid < nb) boff[tid] = x - v;
    if (tid == 63) *totalOut = x;
}

__global__ __launch_bounds__(256) void scan3_kernel(
    const int* __restrict__ data, const int* __restrict__ boff,
    int* __restrict__ rowptr, int* __restrict__ cursor, int n)
{
    int i = blockIdx.x * blockDim.x + threadIdx.x;
    if (i < n) {
        int v = data[i] + boff[i >> 10];
        rowptr[i] = v;
        cursor[i] = v;
    }
}

// Octant-partitioned scatter: block handles dst range [b0,b1) with oct = blockIdx&7.
// Each pair-array line is dirtied by blocks of one octant only (XCD-local L2 ownership
// under round-robin block->XCD dispatch); pairs are single 8B stores.
__global__ __launch_bounds__(256) void scatter_oct(
    const int* __restrict__ src, const int* __restrict__ dst,
    const float* __restrict__ w, int* __restrict__ cursor,
    int2* __restrict__ pairs, int E, int nN)
{
    int oct  = blockIdx.x & 7;
    int grp  = blockIdx.x >> 3;
    int ngrp = gridDim.x >> 3;
    int chunk = (nN + 7) / 8;
    int b0 = oct * chunk;
    int b1 = min(nN, b0 + chunk);
    int i  = grp * blockDim.x + threadIdx.x;
    int ns = ngrp * blockDim.x;
    for (int e = i; e < E; e += ns) {
        int d = dst[e];
        if (d >= b0 && d < b1) {
            int pos = atomicAdd(&cursor[d], 1);
            pairs[pos] = make_int2(src[e], __float_as_int(w[e]));
        }
    }
}

// ---------------------------------------------------------------------------
// MFMA building blocks
// ---------------------------------------------------------------------------
template<int WIDTH, int SA>
__device__ inline void stage_tile(u16* Atile, const u16* __restrict__ src,
                                  int rowbase, int nN, int lane, int colOff)
{
    constexpr int BPR   = WIDTH * 2;
    constexpr int ITERS = (16 * BPR) / 1024;
    #pragma unroll
    for (int it = 0; it < ITERS; ++it) {
        int flat = it * 1024 + lane * 16;
        int row  = flat / BPR;
        int colS = (flat % BPR) >> 1;
        int4 v = make_int4(0, 0, 0, 0);
        int gr = rowbase + row;
        if (gr < nN)
            v = *reinterpret_cast<const int4*>(src + (size_t)gr * WIDTH + colS);
        *reinterpret_cast<int4*>(Atile + row * SA + colOff + colS) = v;
    }
}

template<int NT>
__device__ inline void init_acc(f32x4* acc, const float* __restrict__ bias, int lane)
{
    #pragma unroll
    for (int nt = 0; nt < NT; ++nt) {
        float bv = bias ? bias[nt * 16 + (lane & 15)] : 0.f;
        acc[nt] = (f32x4){bv, bv, bv, bv};
    }
}

template<int KK, int NT, int SA>
__device__ inline void mfma_pass(const u16* Atile, const u16* __restrict__ Wf,
                                 int lane, f32x4* acc)
{
    const u16* ap = Atile + (lane & 15) * SA + ((lane >> 4) << 3);
    #pragma unroll
    for (int kk = 0; kk < KK; ++kk) {
        s16x8 a = *reinterpret_cast<const s16x8*>(ap + kk * 32);
        #pragma unroll
        for (int nt = 0; nt < NT; ++nt) {
            s16x8 b = *reinterpret_cast<const s16x8*>(Wf + ((size_t)(kk * NT + nt) * 64 + lane) * 8);
            acc[nt] = __builtin_amdgcn_mfma_f32_16x16x32_bf16(a, b, acc[nt], 0, 0, 0);
        }
    }
}

template<int NT, int SA, bool RELU>
__device__ inline void store_c_lds(u16* Btile, f32x4* acc, int lane)
{
    int r0 = (lane >> 4) << 2;
    int c  = lane & 15;
    #pragma unroll
    for (int nt = 0; nt < NT; ++nt)
        #pragma unroll
        for (int i = 0; i < 4; ++i) {
            float v = acc[nt][i];
            if (RELU) v = fmaxf(v, 0.f);
            Btile[(r0 + i) * SA + nt * 16 + c] = f2bf(v);
        }
}

template<int NT, int NOUT, bool RELU, bool OBF16>
__device__ inline void store_c_global(void* Y, f32x4* acc, int rowbase, int nN, int lane)
{
    int r0 = rowbase + ((lane >> 4) << 2);
    int c  = lane & 15;
    #pragma unroll
    for (int nt = 0; nt < NT; ++nt) {
        int col = nt * 16 + c;
        #pragma unroll
        for (int i = 0; i < 4; ++i) {
            int r = r0 + i;
            if (r < nN) {
                float v = acc[nt][i];
                if (RELU) v = fmaxf(v, 0.f);
                if (OBF16) ((u16*)Y)[(size_t)r * NOUT + col] = f2bf(v);
                else       ((float*)Y)[(size_t)r * NOUT + col] = v;
            }
        }
    }
}

// Fused front: t1 = xb@W1 ; s_c = relu(xb@Wm1+bm1)@Wm2+bm2  (one xb staging)
__global__ __launch_bounds__(256) void front_kernel(
    const u16* __restrict__ Xb,
    const u16* __restrict__ W1f,
    const u16* __restrict__ Wm1f, const float* __restrict__ bm1,
    const u16* __restrict__ Wm2f, const float* __restrict__ bm2,
    u16* __restrict__ T1, u16* __restrict__ Sc, int nN)
{
    constexpr int SA = 136;
    __shared__ __align__(16) u16 As[4 * 16 * SA];
    __shared__ __align__(16) u16 Bs[4 * 16 * SA];
    int tid = threadIdx.x, w = tid >> 6, lane = tid & 63;
    int rowbase = blockIdx.x * 64 + w * 16;
    u16* At = As + w * 16 * SA;
    u16* Bt = Bs + w * 16 * SA;
    stage_tile<128, SA>(At, Xb, rowbase, nN, lane, 0);
    __syncthreads();
    {
        f32x4 acc[8];
        init_acc<8>(acc, nullptr, lane);
        mfma_pass<4, 8, SA>(At, W1f, lane, acc);
        store_c_global<8, 128, false, true>(T1, acc, rowbase, nN, lane);
    }
    {
        f32x4 acc[8];
        init_acc<8>(acc, bm1, lane);
        mfma_pass<4, 8, SA>(At, Wm1f, lane, acc);
        store_c_lds<8, SA, true>(Bt, acc, lane);
    }
    __syncthreads();
    {
        f32x4 acc[4];
        init_acc<4>(acc, bm2, lane);
        mfma_pass<4, 4, SA>(Bt, Wm2f, lane, acc);
        store_c_global<4, 64, false, true>(Sc, acc, rowbase, nN, lane);
    }
}

// t2 = conv1 @ W2
template<int K, int NOUT, bool RELU, bool OBF16>
__global__ __launch_bounds__(256) void gemm_mfma(
    const u16* __restrict__ Xb, const u16* __restrict__ Wf,
    const float* __restrict__ bias, void* __restrict__ Y, int nN)
{
    constexpr int SA = K + 8;
    __shared__ __align__(16) u16 As[4 * 16 * SA];
    int tid = threadIdx.x, w = tid >> 6, lane = tid & 63;
    int rowbase = blockIdx.x * 64 + w * 16;
    u16* At = As + w * 16 * SA;
    stage_tile<K, SA>(At, Xb, rowbase, nN, lane, 0);
    __syncthreads();
    f32x4 acc[NOUT / 16];
    init_acc<NOUT / 16>(acc, bias, lane);
    mfma_pass<K / 32, NOUT / 16, SA>(At, Wf, lane, acc);
    store_c_global<NOUT / 16, NOUT, RELU, OBF16>(Y, acc, rowbase, nN, lane);
}

// tail: out = relu([s_c|conv1|conv2]@Wh1+bh1) @ Wh2 + bh2  -> fp32
__global__ __launch_bounds__(256) void tail_mfma_kernel(
    const u16* __restrict__ Sc, const u16* __restrict__ C1, const u16* __restrict__ C2,
    const u16* __restrict__ Wh1f, const float* __restrict__ bh1,
    const u16* __restrict__ Wh2f, const float* __restrict__ bh2,
    float* __restrict__ out, int nN)
{
    constexpr int SA1 = 264, SA2 = 136;
    __shared__ __align__(16) u16 As[4 * 16 * SA1];
    __shared__ __align__(16) u16 Bs[4 * 16 * SA2];
    int tid = threadIdx.x, w = tid >> 6, lane = tid & 63;
    int rowbase = blockIdx.x * 64 + w * 16;
    u16* At = As + w * 16 * SA1;
    u16* Bt = Bs + w * 16 * SA2;
    stage_tile<64,  SA1>(At, Sc, rowbase, nN, lane, 0);
    stage_tile<128, SA1>(At, C1, rowbase, nN, lane, 64);
    stage_tile<64,  SA1>(At, C2, rowbase, nN, lane, 192);
    __syncthreads();
    {
        f32x4 acc[8];
        init_acc<8>(acc, bh1, lane);
        mfma_pass<8, 8, SA1>(At, Wh1f, lane, acc);
        store_c_lds<8, SA2, true>(Bt, acc, lane);
    }
    __syncthreads();
    {
        f32x4 acc[4];
        init_acc<4>(acc, bh2, lane);
        mfma_pass<4, 4, SA2>(Bt, Wh2f, lane, acc);
        store_c_global<4, 64, false, false>(out, acc, rowbase, nN, lane);
    }
}

// ---------------------------------------------------------------------------
// CSR SpMM gather (packed pairs), bf16 x, fp32 accum
// ---------------------------------------------------------------------------
template<bool RELU>
__global__ __launch_bounds__(256) void spmm128_bf(
    const int* __restrict__ rowptr, const int2* __restrict__ pairs,
    const u16* __restrict__ x, u16* __restrict__ y, int nN)
{
    int lane = threadIdx.x & 63;
    int row  = (blockIdx.x * blockDim.x + threadIdx.x) >> 6;
    if (row >= nN) return;
    int rs = rowptr[row], re = rowptr[row + 1];
    float a0 = 0.f, a1 = 0.f;
    for (int base = rs; base < re; base += 64) {
        int e = base + lane;
        int2 pr = make_int2(0, 0);
        if (e < re) pr = pairs[e];
        int cnt = min(64, re - base);
        int j = 0;
        for (; j + 4 <= cnt; j += 4) {
            int   s0 = __shfl(pr.x, j+0), s1 = __shfl(pr.x, j+1),
                  s2 = __shfl(pr.x, j+2), s3 = __shfl(pr.x, j+3);
            float w0 = __int_as_float(__shfl(pr.y, j+0)),
                  w1 = __int_as_float(__shfl(pr.y, j+1)),
                  w2 = __int_as_float(__shfl(pr.y, j+2)),
                  w3 = __int_as_float(__shfl(pr.y, j+3));
            u32 u0 = *reinterpret_cast<const u32*>(x + (size_t)s0 * 128 + lane * 2);
            u32 u1 = *reinterpret_cast<const u32*>(x + (size_t)s1 * 128 + lane * 2);
            u32 u2 = *reinterpret_cast<const u32*>(x + (size_t)s2 * 128 + lane * 2);
            u32 u3 = *reinterpret_cast<const u32*>(x + (size_t)s3 * 128 + lane * 2);
            a0 += w0 * bflo(u0); a1 += w0 * bfhi(u0);
            a0 += w1 * bflo(u1); a1 += w1 * bfhi(u1);
            a0 += w2 * bflo(u2); a1 += w2 * bfhi(u2);
            a0 += w3 * bflo(u3); a1 += w3 * bfhi(u3);
        }
        for (; j < cnt; ++j) {
            int   s = __shfl(pr.x, j);
            float ww = __int_as_float(__shfl(pr.y, j));
            u32 u = *reinterpret_cast<const u32*>(x + (size_t)s * 128 + lane * 2);
            a0 += ww * bflo(u); a1 += ww * bfhi(u);
        }
    }
    if (RELU) { a0 = fmaxf(a0, 0.f); a1 = fmaxf(a1, 0.f); }
    u32 o = (u32)f2bf(a0) | ((u32)f2bf(a1) << 16);
    *reinterpret_cast<u32*>(y + (size_t)row * 128 + lane * 2) = o;
}

__global__ __launch_bounds__(256) void spmm64_bf(
    const int* __restrict__ rowptr, const int2* __restrict__ pairs,
    const u16* __restrict__ x, u16* __restrict__ y, int nN)
{
    int lane = threadIdx.x & 63;
    int wp   = (blockIdx.x * blockDim.x + threadIdx.x) >> 6;
    int sub  = lane >> 5, sl = lane & 31;
    int row  = wp * 2 + sub;
    if (wp * 2 >= nN) return;
    bool live = row < nN;
    int rs = live ? rowptr[row] : 0;
    int re = live ? rowptr[row + 1] : 0;
    float a0 = 0.f, a1 = 0.f;
    for (int base = rs; base < re; base += 32) {
        int e = base + sl;
        int2 pr = make_int2(0, 0);
        if (e < re) pr = pairs[e];
        int cnt = min(32, re - base);
        int j = 0;
        for (; j + 4 <= cnt; j += 4) {
            int   s0 = __shfl(pr.x, j+0, 32), s1 = __shfl(pr.x, j+1, 32),
                  s2 = __shfl(pr.x, j+2, 32), s3 = __shfl(pr.x, j+3, 32);
            float w0 = __int_as_float(__shfl(pr.y, j+0, 32)),
                  w1 = __int_as_float(__shfl(pr.y, j+1, 32)),
                  w2 = __int_as_float(__shfl(pr.y, j+2, 32)),
                  w3 = __int_as_float(__shfl(pr.y, j+3, 32));
            u32 u0 = *reinterpret_cast<const u32*>(x + (size_t)s0 * 64 + sl * 2);
            u32 u1 = *reinterpret_cast<const u32*>(x + (size_t)s1 * 64 + sl * 2);
            u32 u2 = *reinterpret_cast<const u32*>(x + (size_t)s2 * 64 + sl * 2);
            u32 u3 = *reinterpret_cast<const u32*>(x + (size_t)s3 * 64 + sl * 2);
            a0 += w0 * bflo(u0); a1 += w0 * bfhi(u0);
            a0 += w1 * bflo(u1); a1 += w1 * bfhi(u1);
            a0 += w2 * bflo(u2); a1 += w2 * bfhi(u2);
            a0 += w3 * bflo(u3); a1 += w3 * bfhi(u3);
        }
        for (; j < cnt; ++j) {
            int   s = __shfl(pr.x, j, 32);
            float ww = __int_as_float(__shfl(pr.y, j, 32));
            u32 u = *reinterpret_cast<const u32*>(x + (size_t)s * 64 + sl * 2);
            a0 += ww * bflo(u); a1 += ww * bfhi(u);
        }
    }
    if (live) {
        u32 o = (u32)f2bf(a0) | ((u32)f2bf(a1) << 16);
        *reinterpret_cast<u32*>(y + (size_t)row * 64 + sl * 2) = o;
    }
}

// ===========================================================================
extern "C" void kernel_launch(void* const* d_in, const int* in_sizes, int n_in,
                              void* d_out, int out_size, void* d_ws, size_t ws_size,
                              hipStream_t stream)
{
    const float* features = (const float*)d_in[0];
    const int*   esrc     = (const int*)d_in[1];
    const int*   edst     = (const int*)d_in[2];
    const float* ew       = (const float*)d_in[3];
    const float* W1  = (const float*)d_in[4];
    const float* W2  = (const float*)d_in[5];
    const float* Wm1 = (const float*)d_in[6];
    const float* bm1 = (const float*)d_in[7];
    const float* Wm2 = (const float*)d_in[8];
    const float* bm2 = (const float*)d_in[9];
    const float* Wh1 = (const float*)d_in[10];
    const float* bh1 = (const float*)d_in[11];
    const float* Wh2 = (const float*)d_in[12];
    const float* bh2 = (const float*)d_in[13];

    int nN = in_sizes[0] / D;   // 50000
    int E  = in_sizes[1];       // 1.6M
    float* out = (float*)d_out;

    // ---- workspace bump allocation ----
    char* base = (char*)d_ws;
    size_t off = 0;
    auto alloc = [&](size_t bytes) -> char* {
        char* p = base + off;
        off += (bytes + 255) & ~(size_t)255;
        return p;
    };
    u16*  xb     = (u16*)alloc((size_t)nN * 128 * 2);  // xb, later conv2b
    u16*  t1b    = (u16*)alloc((size_t)nN * 128 * 2);  // t1b, later t2b
    u16*  conv1b = (u16*)alloc((size_t)nN * 128 * 2);
    u16*  s_cb   = (u16*)alloc((size_t)nN * 64 * 2);
    int2* pairs  = (int2*)alloc((size_t)E * 8);
    int* rowptr  = (int*)alloc(((size_t)nN + 1) * 4);
    int* cursor  = (int*)alloc((size_t)nN * 4);
    int* tmp     = (int*)alloc((size_t)nN * 4);
    int* bsum    = (int*)alloc(64 * 4);
    int* boff    = (int*)alloc(64 * 4);
    u16* W1f  = (u16*)alloc(4 * 8 * 64 * 8 * 2);
    u16* Wm1f = (u16*)alloc(4 * 8 * 64 * 8 * 2);
    u16* W2f  = (u16*)alloc(4 * 4 * 64 * 8 * 2);
    u16* Wm2f = (u16*)alloc(4 * 4 * 64 * 8 * 2);
    u16* Wh2f = (u16*)alloc(4 * 4 * 64 * 8 * 2);
    u16* Wh1f = (u16*)alloc(8 * 8 * 64 * 8 * 2);
    u16* t2b    = t1b;   // [N,64] bf16, t1 dead after conv1 spmm
    u16* conv2b = xb;    // [N,64] bf16, xb dead after front_kernel

    // ---- prep ----
    int n8 = nN * 128 / 8;
    cvt_bf16_kernel<<<(n8 + 255) / 256, 256, 0, stream>>>(features, xb, n8);
    repack_all<<<44, 256, 0, stream>>>(W1, W1f, Wm1, Wm1f, W2, W2f,
                                       Wm2, Wm2f, Wh2, Wh2f, Wh1, Wh1f);

    // ---- CSR build ----
    hipMemsetAsync(tmp, 0, (size_t)nN * 4, stream);
    hist_kernel<<<1024, 256, 0, stream>>>(edst, tmp, E);
    int nb = (nN + 1023) / 1024;
    scan1_kernel<<<nb, 1024, 0, stream>>>(tmp, bsum, nN);
    scan2_kernel<<<1, 64, 0, stream>>>(bsum, boff, nb, rowptr + nN);
    scan3_kernel<<<(nN + 255) / 256, 256, 0, stream>>>(tmp, boff, rowptr, cursor, nN);
    scatter_oct<<<2048, 256, 0, stream>>>(esrc, edst, ew, cursor, pairs, E, nN);

    int gGemm   = (nN + 63) / 64;
    int gSpmm1  = (nN + 3) / 4;
    int gSpmm64 = ((nN + 1) / 2 + 3) / 4;

    // t1 = xb @ W1 ; s_c = relu(xb@Wm1+bm1)@Wm2+bm2
    front_kernel<<<gGemm, 256, 0, stream>>>(xb, W1f, Wm1f, bm1, Wm2f, bm2,
                                            t1b, s_cb, nN);
    // conv1 = relu(A . t1)
    spmm128_bf<true><<<gSpmm1, 256, 0, stream>>>(rowptr, pairs, t1b, conv1b, nN);
    // t2 = conv1 @ W2
    gemm_mfma<128, 64, false, true><<<gGemm, 256, 0, stream>>>(conv1b, W2f, nullptr, t2b, nN);
    // conv2 = A . t2
    spmm64_bf<<<gSpmm64, 256, 0, stream>>>(rowptr, pairs, t2b, conv2b, nN);
    // out = relu([s_c|conv1|conv2]@Wh1+bh1)@Wh2+bh2
    tail_mfma_kernel<<<gGemm, 256, 0, stream>>>(s_cb, conv1b, conv2b,
                                                Wh1f, bh1, Wh2f, bh2, out, nN);
}